// Round 6
// baseline (5843.288 us; speedup 1.0000x reference)
//
#include <hip/hip_runtime.h>
#include <math.h>
#include <float.h>

// Decoder: 32-step greedy GRU decode. B=64, H=E=1024, L=2, V=32000, T=32.
// R4: all GEMMs via mfma_f32_16x16x32_bf16, bf16 hi/lo split (hihi+hilo+lohi).
// R5: 4-wave blocks splitting K=1024 into 4x256 slices + LDS reduce.
// R6: 16-row blocks (2000 logits / 384 gru per layer) -> ~24 waves/CU for
//     2x memory-level parallelism; launch_bounds(256,6). Same math order.

#define B_ 64
#define H_ 1024
#define V_ 32000
#define T_ 32

typedef unsigned short u16;
typedef float f32x4 __attribute__((ext_vector_type(4)));
typedef short s16x8 __attribute__((ext_vector_type(8)));
#define MFMA16 __builtin_amdgcn_mfma_f32_16x16x32_bf16

// workspace byte offsets (all 256-aligned)
#define WOH_B   0UL           // out_w hi bf16 [32000][1024]  (65,536,000 B)
#define WOL_B   65536000UL    // out_w lo
#define WIHH_B  131072000UL   // w_ih hi [2][3072][1024] (12,582,912 B)
#define WIHL_B  143654912UL
#define WHHH_B  156237824UL   // w_hh hi
#define WHHL_B  168820736UL
#define XH_B    181403648UL   // x hi bf16 [64][1024] (131,072 B)
#define XL_B    181534720UL
#define HBH_B   181665792UL   // h hi bf16 [2][64][1024] (262,144 B)
#define HBL_B   181927936UL
#define HF_B    182190080UL   // h f32 [2][64][1024] (524,288 B)
#define GT_B    182714368UL   // g_t f32 [64][6144] (1,572,864 B)
#define PV_B    184287232UL   // pval [2000][64] f32 (512,000 B)
#define PI_B    184799232UL   // pidx [2000][64] i32 (512,000 B)
#define TK_B    185311232UL   // tok [64] i32

#define OUT_H_OFF 65536000L   // 64*32*32000
#define NLOGBLK 2000

__device__ __forceinline__ void bf16split(float x, u16& h, u16& l) {
  unsigned u = __float_as_uint(x);
  unsigned r = u + 0x7fff + ((u >> 16) & 1);          // RTN to bf16
  h = (u16)(r >> 16);
  float hf = __uint_as_float((unsigned)h << 16);
  float rem = x - hf;                                  // exact (Sterbenz)
  unsigned u2 = __float_as_uint(rem);
  unsigned r2 = u2 + 0x7fff + ((u2 >> 16) & 1);
  l = (u16)(r2 >> 16);
}

// fp32 -> (hi,lo) bf16 arrays, grid-stride over float4s.
__global__ void k_convert(const float* __restrict__ src, u16* __restrict__ hi,
                          u16* __restrict__ lo, int n4) {
  int i = blockIdx.x * 256 + threadIdx.x;
  int stride = gridDim.x * 256;
  for (; i < n4; i += stride) {
    float4 v = ((const float4*)src)[i];
    float x[4] = {v.x, v.y, v.z, v.w};
    u16 hh[4], ll[4];
    #pragma unroll
    for (int j = 0; j < 4; ++j) bf16split(x[j], hh[j], ll[j]);
    ushort4 ho; ho.x = hh[0]; ho.y = hh[1]; ho.z = hh[2]; ho.w = hh[3];
    ushort4 lv; lv.x = ll[0]; lv.y = ll[1]; lv.z = ll[2]; lv.w = ll[3];
    ((ushort4*)hi)[i] = ho;
    ((ushort4*)lo)[i] = lv;
  }
}

__global__ void k_init(const float* __restrict__ enc_h, float* __restrict__ hf,
                       u16* __restrict__ hhi, u16* __restrict__ hlo,
                       int* __restrict__ tok) {
  int n = blockIdx.x * 256 + threadIdx.x;   // 512*256 = 131072 = 2*64*1024
  float v = enc_h[n];                       // [l][b][k] layout matches
  hf[n] = v;
  u16 h, l; bf16split(v, h, l);
  hhi[n] = h; hlo[n] = l;
  if (n < B_) tok[n] = 0;                   // START token
}

// Finalize argmax partials, gather+relu embedding, emit x bf16 hi/lo [b][k].
__global__ void k_argmax_embed(const float* __restrict__ emb,
                               const float* __restrict__ pv, const int* __restrict__ pidx,
                               int* __restrict__ tok, u16* __restrict__ xhi,
                               u16* __restrict__ xlo, int do_argmax) {
  __shared__ float sv[1024];
  __shared__ int   si[1024];
  int tid = threadIdx.x;                    // 1024 threads, 1 block
  if (do_argmax) {
    int b = tid & 63, c = tid >> 6;
    float best = -FLT_MAX; int bi = 0x7fffffff;
    for (int i = c; i < NLOGBLK; i += 16) {
      float v = pv[i * 64 + b];
      int  ix = pidx[i * 64 + b];
      if (v > best || (v == best && ix < bi)) { best = v; bi = ix; }
    }
    sv[c * 64 + b] = best; si[c * 64 + b] = bi;
    __syncthreads();
    if (tid < 64) {
      float bv = sv[tid]; int bix = si[tid];
      #pragma unroll
      for (int c2 = 1; c2 < 16; ++c2) {
        float v2 = sv[c2 * 64 + tid]; int i2 = si[c2 * 64 + tid];
        if (v2 > bv || (v2 == bv && i2 < bix)) { bv = v2; bix = i2; }
      }
      tok[tid] = bix;                       // jnp.argmax: lowest index on ties
    }
  }
  __syncthreads();
  int b = tid >> 4, tl = tid & 15;
  const float* erow = emb + (long)tok[b] * H_;
  #pragma unroll
  for (int c = 0; c < 16; ++c) {
    int e = c * 64 + tl * 4;
    float4 v = *(const float4*)(erow + e);
    float x0 = fmaxf(v.x, 0.f), x1 = fmaxf(v.y, 0.f);
    float x2 = fmaxf(v.z, 0.f), x3 = fmaxf(v.w, 0.f);
    u16 h0,h1,h2,h3,l0,l1,l2,l3;
    bf16split(x0,h0,l0); bf16split(x1,h1,l1); bf16split(x2,h2,l2); bf16split(x3,h3,l3);
    ushort4 hv; hv.x=h0; hv.y=h1; hv.z=h2; hv.w=h3;
    ushort4 lv; lv.x=l0; lv.y=l1; lv.z=l2; lv.w=l3;
    *(ushort4*)(xhi + b * 1024 + e) = hv;
    *(ushort4*)(xlo + b * 1024 + e) = lv;
  }
}

// One wave: K-slice (256 of 1024) of D[16 rows][64 batch] = A(16xK).B^T(64xK)^T
// via bf16x3 (hihi+hilo+lohi, same per-acc order as R4/R5). Frag layout
// (16x16x32, verified): A: lane holds A[lane&15][(lane>>4)*8+j]; B likewise;
// D: D[(lane>>4)*4+r][lane&15].
__device__ __forceinline__ void gemm16x64_slice(
    const u16* __restrict__ Ahi, const u16* __restrict__ Alo,
    const u16* __restrict__ Bhi, const u16* __restrict__ Blo,
    int lane, int kbeg, f32x4 (&acc)[4]) {
  int l15 = lane & 15, l4 = lane >> 4;
  const u16* pah = Ahi + l15 * 1024 + l4 * 8 + kbeg;
  const u16* pal = Alo + l15 * 1024 + l4 * 8 + kbeg;
  const u16* pbh = Bhi + l15 * 1024 + l4 * 8 + kbeg;
  const u16* pbl = Blo + l15 * 1024 + l4 * 8 + kbeg;
  #pragma unroll
  for (int k0 = 0; k0 < 256; k0 += 32) {
    s16x8 ah = *(const s16x8*)(pah + k0);
    s16x8 al = *(const s16x8*)(pal + k0);
    #pragma unroll
    for (int nt = 0; nt < 4; ++nt) {
      s16x8 bh = *(const s16x8*)(pbh + nt * 16384 + k0);
      s16x8 bl = *(const s16x8*)(pbl + nt * 16384 + k0);
      acc[nt] = MFMA16(ah, bh, acc[nt], 0, 0, 0);
      acc[nt] = MFMA16(ah, bl, acc[nt], 0, 0, 0);
      acc[nt] = MFMA16(al, bh, acc[nt], 0, 0, 0);
    }
  }
}

// GRU gate GEMM: per layer, 384 blocks of 16 rows (0..191 ih, 192..383 hh).
// 4 waves split K 4x256; LDS reduce; writes g_t[b][row] + bias.
__global__ __launch_bounds__(256, 6) void k_gru(
    const u16* __restrict__ aih_hi, const u16* __restrict__ aih_lo,
    const u16* __restrict__ ahh_hi, const u16* __restrict__ ahh_lo,
    const float* __restrict__ bih, const float* __restrict__ bhh,
    const u16* __restrict__ xb_hi, const u16* __restrict__ xb_lo,
    const u16* __restrict__ hb_hi, const u16* __restrict__ hb_lo,
    float* __restrict__ gt) {
  __shared__ f32x4 sacc[4][64][5];          // [wave][lane][nt], pad->5
  int tid = threadIdx.x;
  int wave = tid >> 6, lane = tid & 63;
  int l15 = lane & 15, l4 = lane >> 4;
  int blk = blockIdx.x;
  bool ih = blk < 192;
  int row0 = (ih ? blk : blk - 192) * 16;
  const u16* Ahi = (ih ? aih_hi : ahh_hi) + (size_t)row0 * 1024;
  const u16* Alo = (ih ? aih_lo : ahh_lo) + (size_t)row0 * 1024;
  const u16* Bhi = ih ? xb_hi : hb_hi;
  const u16* Blo = ih ? xb_lo : hb_lo;
  const float* bias = (ih ? bih : bhh) + row0;
  f32x4 acc[4];
  #pragma unroll
  for (int n = 0; n < 4; ++n) acc[n] = (f32x4){0.f, 0.f, 0.f, 0.f};
  gemm16x64_slice(Ahi, Alo, Bhi, Blo, lane, wave * 256, acc);
  #pragma unroll
  for (int nt = 0; nt < 4; ++nt) sacc[wave][lane][nt] = acc[nt];
  __syncthreads();
  // wave w owns batch tile nt=w: reduce K-slices, add bias, store.
  int grow0 = (ih ? 0 : 3072) + row0;
  int b = wave * 16 + l15;
  f32x4 s = sacc[0][lane][wave];
  #pragma unroll
  for (int j = 1; j < 4; ++j) s += sacc[j][lane][wave];
  f32x4 bs = *(const f32x4*)(bias + l4 * 4);
  *(f32x4*)(gt + (size_t)b * 6144 + grow0 + l4 * 4) = s + bs;
}

// Pointwise GRU gates (torch order r,z,n); updates h f32 + bf16 hi/lo.
__global__ void k_gates(const float* __restrict__ gt, float* __restrict__ hf,
                        u16* __restrict__ hhi, u16* __restrict__ hlo) {
  int n = blockIdx.x * 256 + threadIdx.x;   // 65536 = 64*1024, [b][j]
  int b = n >> 10, j = n & 1023;
  const float* gb = gt + (size_t)b * 6144;
  float ir = gb[j], iz = gb[j + 1024], inn = gb[j + 2048];
  float hr = gb[j + 3072], hz = gb[j + 4096], hn = gb[j + 5120];
  float r = 1.f / (1.f + expf(-(ir + hr)));
  float z = 1.f / (1.f + expf(-(iz + hz)));
  float nn = tanhf(inn + r * hn);
  float ho = hf[n];
  float hv = (1.f - z) * nn + z * ho;
  hf[n] = hv;
  u16 hh, ll; bf16split(hv, hh, ll);
  hhi[n] = hh; hlo[n] = ll;
}

// Logits: 2000 blocks x 4 waves; 16 vocab rows x 64 batch; waves split K 4x256.
// Writes logits (nontemporal) + per-block argmax partials.
__global__ __launch_bounds__(256, 6) void k_logits(
    const u16* __restrict__ whi, const u16* __restrict__ wlo,
    const float* __restrict__ bo, const u16* __restrict__ xhi,
    const u16* __restrict__ xlo, float* __restrict__ pv, int* __restrict__ pidx,
    float* __restrict__ dout, int t) {
  __shared__ f32x4 sacc[4][64][5];          // [wave][lane][nt], pad->5
  int tid = threadIdx.x;
  int wave = tid >> 6, lane = tid & 63;
  int l15 = lane & 15, l4 = lane >> 4;
  int v0 = blockIdx.x * 16;
  f32x4 acc[4];
  #pragma unroll
  for (int n = 0; n < 4; ++n) acc[n] = (f32x4){0.f, 0.f, 0.f, 0.f};
  gemm16x64_slice(whi + (size_t)v0 * 1024, wlo + (size_t)v0 * 1024,
                  xhi, xlo, lane, wave * 256, acc);
  #pragma unroll
  for (int nt = 0; nt < 4; ++nt) sacc[wave][lane][nt] = acc[nt];
  __syncthreads();
  // wave w owns batch tile nt=w: reduce K-slices, add bias, store, argmax.
  long b = wave * 16 + l15;
  f32x4 s = sacc[0][lane][wave];
  #pragma unroll
  for (int j = 1; j < 4; ++j) s += sacc[j][lane][wave];
  f32x4 bs = *(const f32x4*)(bo + v0 + l4 * 4);
  f32x4 out2 = s + bs;
  float* addr = dout + b * (T_ * (long)V_) + (long)t * V_ + v0 + l4 * 4;
  __builtin_nontemporal_store(out2, (f32x4*)addr);
  float bv = -FLT_MAX; int bi = 0;
  #pragma unroll
  for (int r = 0; r < 4; ++r) {
    float v = out2[r];
    if (v > bv) { bv = v; bi = v0 + l4 * 4 + r; }   // ascending idx
  }
  #pragma unroll
  for (int off = 16; off < 64; off <<= 1) {   // combine l4 groups (rows)
    float ov = __shfl_xor(bv, off, 64);
    int   oi = __shfl_xor(bi, off, 64);
    if (ov > bv || (ov == bv && oi < bi)) { bv = ov; bi = oi; }
  }
  if (l4 == 0) {
    pv[blockIdx.x * 64 + wave * 16 + l15] = bv;
    pidx[blockIdx.x * 64 + wave * 16 + l15] = bi;
  }
}

__global__ void k_final(const float* __restrict__ hf, float* __restrict__ dout) {
  int n = blockIdx.x * 256 + threadIdx.x;   // 131072; hf layout == out layout
  dout[OUT_H_OFF + n] = hf[n];
}

extern "C" void kernel_launch(void* const* d_in, const int* in_sizes, int n_in,
                              void* d_out, int out_size, void* d_ws, size_t ws_size,
                              hipStream_t stream) {
  const float* enc_h = (const float*)d_in[1];
  const float* emb   = (const float*)d_in[2];
  const float* w_ih  = (const float*)d_in[3];
  const float* w_hh  = (const float*)d_in[4];
  const float* b_ih  = (const float*)d_in[5];
  const float* b_hh  = (const float*)d_in[6];
  const float* out_w = (const float*)d_in[7];
  const float* out_b = (const float*)d_in[8];
  float* out = (float*)d_out;
  char* wsb = (char*)d_ws;

  u16* woh  = (u16*)(wsb + WOH_B);
  u16* wol  = (u16*)(wsb + WOL_B);
  u16* wihh = (u16*)(wsb + WIHH_B);
  u16* wihl = (u16*)(wsb + WIHL_B);
  u16* whhh = (u16*)(wsb + WHHH_B);
  u16* whhl = (u16*)(wsb + WHHL_B);
  u16* xh   = (u16*)(wsb + XH_B);
  u16* xl   = (u16*)(wsb + XL_B);
  u16* hbh  = (u16*)(wsb + HBH_B);
  u16* hbl  = (u16*)(wsb + HBL_B);
  float* hf = (float*)(wsb + HF_B);
  float* gt = (float*)(wsb + GT_B);
  float* pv = (float*)(wsb + PV_B);
  int* pidx = (int*)(wsb + PI_B);
  int* tok  = (int*)(wsb + TK_B);

  k_convert<<<4096, 256, 0, stream>>>(out_w, woh, wol, 8192000);
  k_convert<<<2048, 256, 0, stream>>>(w_ih, wihh, wihl, 1572864);
  k_convert<<<2048, 256, 0, stream>>>(w_hh, whhh, whhl, 1572864);
  k_init<<<512, 256, 0, stream>>>(enc_h, hf, hbh, hbl, tok);

  for (int t = 0; t < T_; ++t) {
    k_argmax_embed<<<1, 1024, 0, stream>>>(emb, pv, pidx, tok, xh, xl, t > 0);
    for (int l = 0; l < 2; ++l) {
      const u16* bxh = (l == 0) ? xh : hbh;   // layer 1 input = h[0]
      const u16* bxl = (l == 0) ? xl : hbl;
      k_gru<<<384, 256, 0, stream>>>(wihh + (size_t)l * 3145728, wihl + (size_t)l * 3145728,
                                     whhh + (size_t)l * 3145728, whhl + (size_t)l * 3145728,
                                     b_ih + l * 3072, b_hh + l * 3072,
                                     bxh, bxl, hbh + l * 65536, hbl + l * 65536, gt);
      k_gates<<<256, 256, 0, stream>>>(gt, hf + l * 65536, hbh + l * 65536, hbl + l * 65536);
    }
    k_logits<<<NLOGBLK, 256, 0, stream>>>(woh, wol, out_b, hbh + 65536, hbl + 65536,
                                          pv, pidx, out, t);
  }
  k_final<<<512, 256, 0, stream>>>(hf, out);
}

// Round 7
// 3793.674 us; speedup vs baseline: 1.5403x; 1.5403x over previous
//
#include <hip/hip_runtime.h>
#include <math.h>
#include <float.h>

// Decoder: 32-step greedy GRU decode. B=64, H=E=1024, L=2, V=32000, T=32.
// R4: all GEMMs via mfma_f32_16x16x32_bf16, bf16 hi/lo split (hihi+hilo+lohi).
// R5: 4-wave blocks splitting K=1024 into 4x256 slices + LDS reduce. (3.78ms)
// R6 REGRESSED (launch_bounds(,6) VGPR strangle + 16-row blocks): reverted.
// R7: R5 geometry + two-phase LDS reduce (36KB -> 20KB/block) for +blocks/CU.
//     No forced occupancy bounds. FP order identical to R5.

#define B_ 64
#define H_ 1024
#define V_ 32000
#define T_ 32

typedef unsigned short u16;
typedef float f32x4 __attribute__((ext_vector_type(4)));
typedef short s16x8 __attribute__((ext_vector_type(8)));
#define MFMA16 __builtin_amdgcn_mfma_f32_16x16x32_bf16

// workspace byte offsets (all 256-aligned)
#define WOH_B   0UL           // out_w hi bf16 [32000][1024]  (65,536,000 B)
#define WOL_B   65536000UL    // out_w lo
#define WIHH_B  131072000UL   // w_ih hi [2][3072][1024] (12,582,912 B)
#define WIHL_B  143654912UL
#define WHHH_B  156237824UL   // w_hh hi
#define WHHL_B  168820736UL
#define XH_B    181403648UL   // x hi bf16 [64][1024] (131,072 B)
#define XL_B    181534720UL
#define HBH_B   181665792UL   // h hi bf16 [2][64][1024] (262,144 B)
#define HBL_B   181927936UL
#define HF_B    182190080UL   // h f32 [2][64][1024] (524,288 B)
#define GT_B    182714368UL   // g_t f32 [64][6144] (1,572,864 B)
#define PV_B    184287232UL   // pval [1000][64] f32
#define PI_B    184543232UL   // pidx [1000][64] i32
#define TK_B    184799232UL   // tok [64] i32

#define OUT_H_OFF 65536000L   // 64*32*32000

__device__ __forceinline__ void bf16split(float x, u16& h, u16& l) {
  unsigned u = __float_as_uint(x);
  unsigned r = u + 0x7fff + ((u >> 16) & 1);          // RTN to bf16
  h = (u16)(r >> 16);
  float hf = __uint_as_float((unsigned)h << 16);
  float rem = x - hf;                                  // exact (Sterbenz)
  unsigned u2 = __float_as_uint(rem);
  unsigned r2 = u2 + 0x7fff + ((u2 >> 16) & 1);
  l = (u16)(r2 >> 16);
}

// fp32 -> (hi,lo) bf16 arrays, grid-stride over float4s.
__global__ void k_convert(const float* __restrict__ src, u16* __restrict__ hi,
                          u16* __restrict__ lo, int n4) {
  int i = blockIdx.x * 256 + threadIdx.x;
  int stride = gridDim.x * 256;
  for (; i < n4; i += stride) {
    float4 v = ((const float4*)src)[i];
    float x[4] = {v.x, v.y, v.z, v.w};
    u16 hh[4], ll[4];
    #pragma unroll
    for (int j = 0; j < 4; ++j) bf16split(x[j], hh[j], ll[j]);
    ushort4 ho; ho.x = hh[0]; ho.y = hh[1]; ho.z = hh[2]; ho.w = hh[3];
    ushort4 lv; lv.x = ll[0]; lv.y = ll[1]; lv.z = ll[2]; lv.w = ll[3];
    ((ushort4*)hi)[i] = ho;
    ((ushort4*)lo)[i] = lv;
  }
}

__global__ void k_init(const float* __restrict__ enc_h, float* __restrict__ hf,
                       u16* __restrict__ hhi, u16* __restrict__ hlo,
                       int* __restrict__ tok) {
  int n = blockIdx.x * 256 + threadIdx.x;   // 512*256 = 131072 = 2*64*1024
  float v = enc_h[n];                       // [l][b][k] layout matches
  hf[n] = v;
  u16 h, l; bf16split(v, h, l);
  hhi[n] = h; hlo[n] = l;
  if (n < B_) tok[n] = 0;                   // START token
}

// Finalize argmax partials, gather+relu embedding, emit x bf16 hi/lo [b][k].
__global__ void k_argmax_embed(const float* __restrict__ emb,
                               const float* __restrict__ pv, const int* __restrict__ pidx,
                               int* __restrict__ tok, u16* __restrict__ xhi,
                               u16* __restrict__ xlo, int do_argmax) {
  __shared__ float sv[1024];
  __shared__ int   si[1024];
  int tid = threadIdx.x;                    // 1024 threads, 1 block
  if (do_argmax) {
    int b = tid & 63, c = tid >> 6;
    float best = -FLT_MAX; int bi = 0x7fffffff;
    for (int i = c; i < 1000; i += 16) {
      float v = pv[i * 64 + b];
      int  ix = pidx[i * 64 + b];
      if (v > best || (v == best && ix < bi)) { best = v; bi = ix; }
    }
    sv[c * 64 + b] = best; si[c * 64 + b] = bi;
    __syncthreads();
    if (tid < 64) {
      float bv = sv[tid]; int bix = si[tid];
      #pragma unroll
      for (int c2 = 1; c2 < 16; ++c2) {
        float v2 = sv[c2 * 64 + tid]; int i2 = si[c2 * 64 + tid];
        if (v2 > bv || (v2 == bv && i2 < bix)) { bv = v2; bix = i2; }
      }
      tok[tid] = bix;                       // jnp.argmax: lowest index on ties
    }
  }
  __syncthreads();
  int b = tid >> 4, tl = tid & 15;
  const float* erow = emb + (long)tok[b] * H_;
  #pragma unroll
  for (int c = 0; c < 16; ++c) {
    int e = c * 64 + tl * 4;
    float4 v = *(const float4*)(erow + e);
    float x0 = fmaxf(v.x, 0.f), x1 = fmaxf(v.y, 0.f);
    float x2 = fmaxf(v.z, 0.f), x3 = fmaxf(v.w, 0.f);
    u16 h0,h1,h2,h3,l0,l1,l2,l3;
    bf16split(x0,h0,l0); bf16split(x1,h1,l1); bf16split(x2,h2,l2); bf16split(x3,h3,l3);
    ushort4 hv; hv.x=h0; hv.y=h1; hv.z=h2; hv.w=h3;
    ushort4 lv; lv.x=l0; lv.y=l1; lv.z=l2; lv.w=l3;
    *(ushort4*)(xhi + b * 1024 + e) = hv;
    *(ushort4*)(xlo + b * 1024 + e) = lv;
  }
}

// One wave computes a K-slice (256 of 1024) of D[32 rows][64 batch] =
// A(32xK) . B^T(64xK)^T via bf16x3. Frag layout (16x16x32, verified R4):
// A: lane holds A[lane&15][(lane>>4)*8 + j]; B: B^T[lane&15][(lane>>4)*8 + j];
// D: D[(lane>>4)*4 + r][lane&15].
__device__ __forceinline__ void gemm32x64_slice(
    const u16* __restrict__ Ahi, const u16* __restrict__ Alo,
    const u16* __restrict__ Bhi, const u16* __restrict__ Blo,
    int lane, int kbeg, f32x4 (&acc)[2][4]) {
  int l15 = lane & 15, l4 = lane >> 4;
  const u16* pah = Ahi + l15 * 1024 + l4 * 8 + kbeg;
  const u16* pal = Alo + l15 * 1024 + l4 * 8 + kbeg;
  const u16* pbh = Bhi + l15 * 1024 + l4 * 8 + kbeg;
  const u16* pbl = Blo + l15 * 1024 + l4 * 8 + kbeg;
  #pragma unroll 2
  for (int k0 = 0; k0 < 256; k0 += 32) {
    s16x8 ah0 = *(const s16x8*)(pah + k0);
    s16x8 ah1 = *(const s16x8*)(pah + 16 * 1024 + k0);
    s16x8 al0 = *(const s16x8*)(pal + k0);
    s16x8 al1 = *(const s16x8*)(pal + 16 * 1024 + k0);
    #pragma unroll
    for (int nt = 0; nt < 4; ++nt) {
      s16x8 bh = *(const s16x8*)(pbh + nt * 16 * 1024 + k0);
      s16x8 bl = *(const s16x8*)(pbl + nt * 16 * 1024 + k0);
      acc[0][nt] = MFMA16(ah0, bh, acc[0][nt], 0, 0, 0);
      acc[1][nt] = MFMA16(ah1, bh, acc[1][nt], 0, 0, 0);
      acc[0][nt] = MFMA16(ah0, bl, acc[0][nt], 0, 0, 0);
      acc[1][nt] = MFMA16(ah1, bl, acc[1][nt], 0, 0, 0);
      acc[0][nt] = MFMA16(al0, bh, acc[0][nt], 0, 0, 0);
      acc[1][nt] = MFMA16(al1, bh, acc[1][nt], 0, 0, 0);
    }
  }
}

// GRU gate GEMM: blocks 0..95 -> W_ih rows (vs layer input x), 96..191 -> W_hh
// rows (vs h state). 4 waves split K; two-phase LDS reduce (20KB).
__global__ __launch_bounds__(256) void k_gru(
    const u16* __restrict__ aih_hi, const u16* __restrict__ aih_lo,
    const u16* __restrict__ ahh_hi, const u16* __restrict__ ahh_lo,
    const float* __restrict__ bih, const float* __restrict__ bhh,
    const u16* __restrict__ xb_hi, const u16* __restrict__ xb_lo,
    const u16* __restrict__ hb_hi, const u16* __restrict__ hb_lo,
    float* __restrict__ gt) {
  __shared__ f32x4 sacc[4][64][5];          // [wave][lane][nt], pad->5 (20KB)
  int tid = threadIdx.x;
  int wave = tid >> 6, lane = tid & 63;
  int l15 = lane & 15, l4 = lane >> 4;
  int blk = blockIdx.x;
  bool ih = blk < 96;
  int row0 = (ih ? blk : blk - 96) * 32;
  const u16* Ahi = (ih ? aih_hi : ahh_hi) + (size_t)row0 * 1024;
  const u16* Alo = (ih ? aih_lo : ahh_lo) + (size_t)row0 * 1024;
  const u16* Bhi = ih ? xb_hi : hb_hi;
  const u16* Blo = ih ? xb_lo : hb_lo;
  const float* bias = (ih ? bih : bhh) + row0;
  f32x4 acc[2][4];
  #pragma unroll
  for (int m = 0; m < 2; ++m)
    #pragma unroll
    for (int n = 0; n < 4; ++n) acc[m][n] = (f32x4){0.f, 0.f, 0.f, 0.f};
  gemm32x64_slice(Ahi, Alo, Bhi, Blo, lane, wave * 256, acc);
  // two-phase reduce: mt=0 then mt=1 through the same 20KB buffer.
  #pragma unroll
  for (int nt = 0; nt < 4; ++nt) sacc[wave][lane][nt] = acc[0][nt];
  __syncthreads();
  f32x4 s0 = sacc[0][lane][wave];
  #pragma unroll
  for (int j = 1; j < 4; ++j) s0 += sacc[j][lane][wave];
  __syncthreads();
  #pragma unroll
  for (int nt = 0; nt < 4; ++nt) sacc[wave][lane][nt] = acc[1][nt];
  __syncthreads();
  f32x4 s1 = sacc[0][lane][wave];
  #pragma unroll
  for (int j = 1; j < 4; ++j) s1 += sacc[j][lane][wave];
  // wave w owns batch tile nt=w: add bias, store.
  int grow0 = (ih ? 0 : 3072) + row0;
  int b = wave * 16 + l15;
  f32x4 bs0 = *(const f32x4*)(bias + l4 * 4);
  f32x4 bs1 = *(const f32x4*)(bias + 16 + l4 * 4);
  *(f32x4*)(gt + (size_t)b * 6144 + grow0 + l4 * 4) = s0 + bs0;
  *(f32x4*)(gt + (size_t)b * 6144 + grow0 + 16 + l4 * 4) = s1 + bs1;
}

// Pointwise GRU gates (torch order r,z,n); updates h f32 + bf16 hi/lo.
__global__ void k_gates(const float* __restrict__ gt, float* __restrict__ hf,
                        u16* __restrict__ hhi, u16* __restrict__ hlo) {
  int n = blockIdx.x * 256 + threadIdx.x;   // 65536 = 64*1024, [b][j]
  int b = n >> 10, j = n & 1023;
  const float* gb = gt + (size_t)b * 6144;
  float ir = gb[j], iz = gb[j + 1024], inn = gb[j + 2048];
  float hr = gb[j + 3072], hz = gb[j + 4096], hn = gb[j + 5120];
  float r = 1.f / (1.f + expf(-(ir + hr)));
  float z = 1.f / (1.f + expf(-(iz + hz)));
  float nn = tanhf(inn + r * hn);
  float ho = hf[n];
  float hv = (1.f - z) * nn + z * ho;
  hf[n] = hv;
  u16 hh, ll; bf16split(hv, hh, ll);
  hhi[n] = hh; hlo[n] = ll;
}

// Logits: 1000 blocks x 4 waves; 32 vocab rows x 64 batch; waves split K 4x256.
// Two-phase LDS reduce (20KB); logits (nontemporal) + argmax partials.
__global__ __launch_bounds__(256) void k_logits(
    const u16* __restrict__ whi, const u16* __restrict__ wlo,
    const float* __restrict__ bo, const u16* __restrict__ xhi,
    const u16* __restrict__ xlo, float* __restrict__ pv, int* __restrict__ pidx,
    float* __restrict__ dout, int t) {
  __shared__ f32x4 sacc[4][64][5];          // [wave][lane][nt], pad->5 (20KB)
  int tid = threadIdx.x;
  int wave = tid >> 6, lane = tid & 63;
  int l15 = lane & 15, l4 = lane >> 4;
  int v0 = blockIdx.x * 32;
  f32x4 acc[2][4];
  #pragma unroll
  for (int m = 0; m < 2; ++m)
    #pragma unroll
    for (int n = 0; n < 4; ++n) acc[m][n] = (f32x4){0.f, 0.f, 0.f, 0.f};
  gemm32x64_slice(whi + (size_t)v0 * 1024, wlo + (size_t)v0 * 1024,
                  xhi, xlo, lane, wave * 256, acc);
  // two-phase reduce: mt=0 then mt=1 through the same 20KB buffer.
  #pragma unroll
  for (int nt = 0; nt < 4; ++nt) sacc[wave][lane][nt] = acc[0][nt];
  __syncthreads();
  f32x4 s0 = sacc[0][lane][wave];
  #pragma unroll
  for (int j = 1; j < 4; ++j) s0 += sacc[j][lane][wave];
  __syncthreads();
  #pragma unroll
  for (int nt = 0; nt < 4; ++nt) sacc[wave][lane][nt] = acc[1][nt];
  __syncthreads();
  f32x4 s1 = sacc[0][lane][wave];
  #pragma unroll
  for (int j = 1; j < 4; ++j) s1 += sacc[j][lane][wave];
  // wave w owns batch tile nt=w: add bias, store, argmax partial.
  long b = wave * 16 + l15;
  f32x4 out0 = s0 + *(const f32x4*)(bo + v0 + l4 * 4);
  f32x4 out1 = s1 + *(const f32x4*)(bo + v0 + 16 + l4 * 4);
  float* addr = dout + b * (T_ * (long)V_) + (long)t * V_ + v0 + l4 * 4;
  __builtin_nontemporal_store(out0, (f32x4*)addr);
  __builtin_nontemporal_store(out1, (f32x4*)(addr + 16));
  float bv = -FLT_MAX; int bi = 0;
  #pragma unroll
  for (int r = 0; r < 4; ++r) {             // mt=0 then mt=1: ascending idx
    float v = out0[r];
    if (v > bv) { bv = v; bi = v0 + l4 * 4 + r; }
  }
  #pragma unroll
  for (int r = 0; r < 4; ++r) {
    float v = out1[r];
    if (v > bv) { bv = v; bi = v0 + 16 + l4 * 4 + r; }
  }
  #pragma unroll
  for (int off = 16; off < 64; off <<= 1) {   // combine l4 groups (rows)
    float ov = __shfl_xor(bv, off, 64);
    int   oi = __shfl_xor(bi, off, 64);
    if (ov > bv || (ov == bv && oi < bi)) { bv = ov; bi = oi; }
  }
  if (l4 == 0) {
    pv[blockIdx.x * 64 + wave * 16 + l15] = bv;
    pidx[blockIdx.x * 64 + wave * 16 + l15] = bi;
  }
}

__global__ void k_final(const float* __restrict__ hf, float* __restrict__ dout) {
  int n = blockIdx.x * 256 + threadIdx.x;   // 131072; hf layout == out layout
  dout[OUT_H_OFF + n] = hf[n];
}

extern "C" void kernel_launch(void* const* d_in, const int* in_sizes, int n_in,
                              void* d_out, int out_size, void* d_ws, size_t ws_size,
                              hipStream_t stream) {
  const float* enc_h = (const float*)d_in[1];
  const float* emb   = (const float*)d_in[2];
  const float* w_ih  = (const float*)d_in[3];
  const float* w_hh  = (const float*)d_in[4];
  const float* b_ih  = (const float*)d_in[5];
  const float* b_hh  = (const float*)d_in[6];
  const float* out_w = (const float*)d_in[7];
  const float* out_b = (const float*)d_in[8];
  float* out = (float*)d_out;
  char* wsb = (char*)d_ws;

  u16* woh  = (u16*)(wsb + WOH_B);
  u16* wol  = (u16*)(wsb + WOL_B);
  u16* wihh = (u16*)(wsb + WIHH_B);
  u16* wihl = (u16*)(wsb + WIHL_B);
  u16* whhh = (u16*)(wsb + WHHH_B);
  u16* whhl = (u16*)(wsb + WHHL_B);
  u16* xh   = (u16*)(wsb + XH_B);
  u16* xl   = (u16*)(wsb + XL_B);
  u16* hbh  = (u16*)(wsb + HBH_B);
  u16* hbl  = (u16*)(wsb + HBL_B);
  float* hf = (float*)(wsb + HF_B);
  float* gt = (float*)(wsb + GT_B);
  float* pv = (float*)(wsb + PV_B);
  int* pidx = (int*)(wsb + PI_B);
  int* tok  = (int*)(wsb + TK_B);

  k_convert<<<4096, 256, 0, stream>>>(out_w, woh, wol, 8192000);
  k_convert<<<2048, 256, 0, stream>>>(w_ih, wihh, wihl, 1572864);
  k_convert<<<2048, 256, 0, stream>>>(w_hh, whhh, whhl, 1572864);
  k_init<<<512, 256, 0, stream>>>(enc_h, hf, hbh, hbl, tok);

  for (int t = 0; t < T_; ++t) {
    k_argmax_embed<<<1, 1024, 0, stream>>>(emb, pv, pidx, tok, xh, xl, t > 0);
    for (int l = 0; l < 2; ++l) {
      const u16* bxh = (l == 0) ? xh : hbh;   // layer 1 input = h[0]
      const u16* bxl = (l == 0) ? xl : hbl;
      k_gru<<<192, 256, 0, stream>>>(wihh + (size_t)l * 3145728, wihl + (size_t)l * 3145728,
                                     whhh + (size_t)l * 3145728, whhl + (size_t)l * 3145728,
                                     b_ih + l * 3072, b_hh + l * 3072,
                                     bxh, bxl, hbh + l * 65536, hbl + l * 65536, gt);
      k_gates<<<256, 256, 0, stream>>>(gt, hf + l * 65536, hbh + l * 65536, hbl + l * 65536);
    }
    k_logits<<<1000, 256, 0, stream>>>(woh, wol, out_b, hbh + 65536, hbl + 65536,
                                       pv, pidx, out, t);
  }
  k_final<<<512, 256, 0, stream>>>(hf, out);
}